// Round 8
// baseline (4898.326 us; speedup 1.0000x reference)
//
#include <hip/hip_runtime.h>
#include <math.h>

#define TPB 256
typedef unsigned short u16;
typedef unsigned int u32;
typedef __bf16 bf16x8 __attribute__((ext_vector_type(8)));
typedef float f32x4 __attribute__((ext_vector_type(4)));

namespace {
constexpr int NTOK  = 1024;
constexpr int IND   = 512;
constexpr int HD    = 1024;
constexpr int OUTD  = 512;
constexpr int NE    = 8;
constexpr int NSLOT = 2048;
}

// ---------------- bf16 split helpers (RNE) ----------------
__device__ __forceinline__ u16 f2bf(float f) {
  u32 x = __float_as_uint(f);
  x += 0x7fffu + ((x >> 16) & 1u);
  return (u16)(x >> 16);
}
__device__ __forceinline__ float bf2f(u16 u) { return __uint_as_float(((u32)u) << 16); }
__device__ __forceinline__ void split2(float v, u16& h, u16& l) {
  h = f2bf(v);
  l = f2bf(v - bf2f(h));
}

__device__ __forceinline__ void gll16(const void* g, void* l) {
  __builtin_amdgcn_global_load_lds((const __attribute__((address_space(1))) void*)g,
                                   (__attribute__((address_space(3))) void*)l, 16, 0, 0);
}

// =====================================================================
//                       SPLIT-BF16 MFMA PATH
// =====================================================================

// transpose + split + TILE-PACK (BN=64): in[z][K][N] f32 -> packed B planes.
// Tile (nb = n>>6, ks = k>>6) is 4096 u16 contiguous; element (n,k) at
// tile*4096 + ((n&63)*8 + (((k>>3)&7) ^ (n&7)))*8 + (k&7)  — exactly the
// GEMM staging slot order (XOR swizzle baked in).
__global__ __launch_bounds__(TPB)
void transpose_split(const float* __restrict__ in, u16* __restrict__ ohi,
                     u16* __restrict__ olo, int K, int N)
{
  const int z = blockIdx.z;
  in  += (size_t)z * K * N;
  ohi += (size_t)z * K * N;
  olo += (size_t)z * K * N;
  __shared__ float tile[32][33];
  const int k0 = blockIdx.y * 32, n0 = blockIdx.x * 32;
  const int tx = threadIdx.x & 31, ty = threadIdx.x >> 5;
#pragma unroll
  for (int i = 0; i < 4; ++i) {
    int k = ty + i * 8;
    tile[k][tx] = in[(size_t)(k0 + k) * N + n0 + tx];
  }
  __syncthreads();
#pragma unroll
  for (int i = 0; i < 4; ++i) {
    int n = ty + i * 8;
    float v = tile[tx][n];                 // element (k = k0+tx, n = n0+n)
    u16 h, l; split2(v, h, l);
    int kk = k0 + tx, nn = n0 + n;
    size_t o = ((size_t)((nn >> 6) * (K >> 6) + (kk >> 6)) << 12)
             + (((nn & 63) * 8 + (((kk >> 3) & 7) ^ (nn & 7))) << 3) + (kk & 7);
    ohi[o] = h; olo[o] = l;
  }
}

// row split (no transpose): in[M][K] f32 -> hi/lo bf16 same layout
__global__ __launch_bounds__(TPB)
void split_rows(const float* __restrict__ in, u16* __restrict__ oh,
                u16* __restrict__ ol, int nelem)
{
  int i = blockIdx.x * TPB + threadIdx.x;
  if (i * 4 >= nelem) return;
  float4 v = ((const float4*)in)[i];
  ushort4 H, L;
  split2(v.x, H.x, L.x); split2(v.y, H.y, L.y);
  split2(v.z, H.z, L.z); split2(v.w, H.w, L.w);
  ((ushort4*)oh)[i] = H;
  ((ushort4*)ol)[i] = L;
}

// zero split-K scratch (Cp) + tile counters
__global__ __launch_bounds__(TPB)
void zero_scratch(float4* __restrict__ Cp4, int4* __restrict__ cnt4)
{
  int i = blockIdx.x * TPB + threadIdx.x;
  if (i < NSLOT * HD / 4) Cp4[i] = make_float4(0.f, 0.f, 0.f, 0.f);
  if (i < 1024) cnt4[i] = make_int4(0, 0, 0, 0);
}

// Split-bf16 MFMA GEMM with SPLIT-K=2: C = act(A@B + bias).
// BM=64 BN=64 BK=64, 4 waves (2x2), wave tile 32x32, 3 MFMAs per frag pair.
// blockIdx.z = (expert<<1)|khalf. Each half atomically accumulates its fp32
// partial into Cp (2 commutative adds per element -> exact & deterministic);
// a tile counter elects the SECOND block to run the epilogue (bias/relu/
// split-store) and re-zero Cp+counter for the next dispatch.
// Single 32KB LDS buffer (m97 2-barrier loop) -> 4+ blocks/CU for TLP.
template<bool RELU, bool GROUPED, bool GATHER, bool SPLIT_OUT>
__global__ __launch_bounds__(TPB, 4)
void gemm_split(const u16* __restrict__ Ah, const u16* __restrict__ Al,
                const int* __restrict__ gatherIdx,
                const u16* __restrict__ Bh, const u16* __restrict__ Bl,
                const float* __restrict__ bias,
                float* __restrict__ Cf, u16* __restrict__ Ch, u16* __restrict__ Cl,
                const int* __restrict__ seg_off, const int* __restrict__ seg_cnt,
                float* __restrict__ Cp, int* __restrict__ cnt_arr,
                int M, int K, int N)
{
  const int zz = blockIdx.z;
  const int e  = GROUPED ? (zz >> 1) : 0;
  const int kh = zz & 1;
  int cnt = M, base = 0;
  if (GROUPED) { cnt = seg_cnt[e]; base = seg_off[e]; }
  const int tm = blockIdx.y, tn = blockIdx.x;
  if (tm * 64 >= cnt) return;

  __shared__ u16 smem[16384];  // AH 4096 | AL 4096 | BH 4096 | BL 4096 = 32KB
  constexpr int AHo = 0, ALo = 4096, BHo = 8192, BLo = 12288;

  const int t = threadIdx.x;
  const int wid = t >> 6, lane = t & 63;
  const int wr = wid >> 1, wc = wid & 1;   // 2x2 wave grid, wave tile 32x32

  const int Khalf = K >> 1;
  const int kbase = kh * Khalf;
  const int NS = Khalf >> 6;

  // A staging: row-major source, swizzled k-block; 2 slots/thread
  const u16* aph[2]; const u16* apl[2];
#pragma unroll
  for (int i = 0; i < 2; ++i) {
    int slot = t + i * TPB;
    int row = slot >> 3, kblk = slot & 7;
    int kbs = kblk ^ (row & 7);
    int row_in = tm * 64 + row;
    int rv = row_in < cnt ? row_in : 0;
    int src;
    if (GATHER)      src = gatherIdx[base + rv];
    else             src = GROUPED ? base + rv : rv;
    size_t off = (size_t)src * K + kbase + kbs * 8;
    aph[i] = Ah + off; apl[i] = Al + off;
  }
  // B staging: tile-packed source — slot-linear contiguous.
  const u16* bsh; const u16* bsl;
  {
    size_t pb = ((size_t)((GROUPED ? e : 0) * (N >> 6) + tn) * (K >> 6)) << 12;
    bsh = Bh + pb; bsl = Bl + pb;
  }

  auto stage = [&](int ks) {   // 8 loads/thread (32KB total)
#pragma unroll
    for (int i = 0; i < 2; ++i) {
      int so = (t + i * TPB) * 8;
      gll16(aph[i] + (ks << 6), &smem[AHo + so]);
      gll16(apl[i] + (ks << 6), &smem[ALo + so]);
    }
    const size_t tb = ((size_t)(kbase >> 6) + ks) << 12;
#pragma unroll
    for (int i = 0; i < 2; ++i) {
      int so = (t + i * TPB) * 8;
      gll16(bsh + tb + so, &smem[BHo + so]);
      gll16(bsl + tb + so, &smem[BLo + so]);
    }
  };

  f32x4 acc[2][2];
#pragma unroll
  for (int i = 0; i < 2; ++i)
#pragma unroll
    for (int j = 0; j < 2; ++j) acc[i][j] = (f32x4){0.f, 0.f, 0.f, 0.f};

  auto compute = [&]() {
#pragma unroll
    for (int s = 0; s < 2; ++s) {
      const int kb = s * 4 + (lane >> 4);
      bf16x8 fah[2], fal[2];
#pragma unroll
      for (int fr = 0; fr < 2; ++fr) {
        int ar = wr * 32 + fr * 16 + (lane & 15);
        int off = ar * 64 + ((kb ^ (ar & 7)) << 3);
        fah[fr] = *(const bf16x8*)&smem[AHo + off];
        fal[fr] = *(const bf16x8*)&smem[ALo + off];
      }
      bf16x8 fbh[2], fbl[2];
#pragma unroll
      for (int fc = 0; fc < 2; ++fc) {
        int bn = wc * 32 + fc * 16 + (lane & 15);
        int off = bn * 64 + ((kb ^ (bn & 7)) << 3);
        fbh[fc] = *(const bf16x8*)&smem[BHo + off];
        fbl[fc] = *(const bf16x8*)&smem[BLo + off];
      }
      __builtin_amdgcn_s_setprio(1);
#pragma unroll
      for (int fr = 0; fr < 2; ++fr)
#pragma unroll
        for (int fc = 0; fc < 2; ++fc) {
          acc[fr][fc] = __builtin_amdgcn_mfma_f32_16x16x32_bf16(fah[fr], fbh[fc], acc[fr][fc], 0, 0, 0);
          acc[fr][fc] = __builtin_amdgcn_mfma_f32_16x16x32_bf16(fah[fr], fbl[fc], acc[fr][fc], 0, 0, 0);
          acc[fr][fc] = __builtin_amdgcn_mfma_f32_16x16x32_bf16(fal[fr], fbh[fc], acc[fr][fc], 0, 0, 0);
        }
      __builtin_amdgcn_s_setprio(0);
    }
  };

  // m97-style single-buffer K-loop: inter-block TLP (4+/CU) hides the drain.
  for (int ks = 0; ks < NS; ++ks) {
    stage(ks);
    __syncthreads();     // vmcnt(0) drain + barrier
    compute();
    __syncthreads();     // LDS safe for next stage
  }

  // deterministic fp32 partial accumulate (2 commutative adds per element)
#pragma unroll
  for (int fr = 0; fr < 2; ++fr)
#pragma unroll
    for (int q = 0; q < 4; ++q) {
      int row_in = tm * 64 + wr * 32 + fr * 16 + ((lane >> 4) << 2) + q;
      if (row_in >= cnt) continue;
      size_t orow = (size_t)(GROUPED ? base + row_in : row_in);
#pragma unroll
      for (int fc = 0; fc < 2; ++fc) {
        int col = tn * 64 + wc * 32 + fc * 16 + (lane & 15);
        atomicAdd(&Cp[orow * N + col], acc[fr][fc][q]);
      }
    }

  __threadfence();
  __syncthreads();
  __shared__ int elect;
  if (t == 0) {
    int tile_id = (GROUPED ? ((e << 5) + tm) : tm) * 16 + tn;
    elect = atomicAdd(&cnt_arr[tile_id], 1);
    if (elect == 1) cnt_arr[tile_id] = 0;   // winner resets for next dispatch
  }
  __syncthreads();
  if (elect != 1) return;
  __threadfence();

  // epilogue (winner only): bias + relu + store, re-zero scratch
  const float* bp = bias + (GROUPED ? (size_t)e * N : 0);
#pragma unroll
  for (int fr = 0; fr < 2; ++fr) {
#pragma unroll
    for (int q = 0; q < 4; ++q) {
      int row_in = tm * 64 + wr * 32 + fr * 16 + ((lane >> 4) << 2) + q;
      if (row_in >= cnt) continue;
      size_t orow = (size_t)(GROUPED ? base + row_in : row_in);
#pragma unroll
      for (int fc = 0; fc < 2; ++fc) {
        int col = tn * 64 + wc * 32 + fc * 16 + (lane & 15);
        size_t idx = orow * N + col;
        float v = Cp[idx] + bp[col];
        Cp[idx] = 0.f;
        if (RELU) v = fmaxf(v, 0.f);
        if (SPLIT_OUT) {
          u16 h, l; split2(v, h, l);
          Ch[idx] = h;
          Cl[idx] = l;
        } else {
          Cf[idx] = v;
        }
      }
    }
  }
}

// layer-0 gating: logits = (hi+lo) @ w_gate, stable top-2 + softmax (vectorized)
__global__ __launch_bounds__(TPB)
void gate_split(const u16* __restrict__ hh, const u16* __restrict__ hl,
                const float* __restrict__ w_gate,
                int* __restrict__ eidx, float* __restrict__ gval)
{
  const int b = blockIdx.x, t = threadIdx.x;
  ushort4 H = ((const ushort4*)(hh + (size_t)b * HD))[t];
  ushort4 L = ((const ushort4*)(hl + (size_t)b * HD))[t];
  float hv[4] = { bf2f(H.x) + bf2f(L.x), bf2f(H.y) + bf2f(L.y),
                  bf2f(H.z) + bf2f(L.z), bf2f(H.w) + bf2f(L.w) };
  float acc[NE] = {};
  const int i0 = t * 4;
#pragma unroll
  for (int j = 0; j < 4; ++j) {
    const float4* wg = (const float4*)(w_gate + (size_t)(i0 + j) * NE);
    float4 w0 = wg[0], w1 = wg[1];
    acc[0] = fmaf(hv[j], w0.x, acc[0]); acc[1] = fmaf(hv[j], w0.y, acc[1]);
    acc[2] = fmaf(hv[j], w0.z, acc[2]); acc[3] = fmaf(hv[j], w0.w, acc[3]);
    acc[4] = fmaf(hv[j], w1.x, acc[4]); acc[5] = fmaf(hv[j], w1.y, acc[5]);
    acc[6] = fmaf(hv[j], w1.z, acc[6]); acc[7] = fmaf(hv[j], w1.w, acc[7]);
  }
  __shared__ float red[TPB][NE];
#pragma unroll
  for (int e = 0; e < NE; ++e) red[t][e] = acc[e];
  __syncthreads();
  for (int s = TPB / 2; s > 0; s >>= 1) {
    if (t < s) {
#pragma unroll
      for (int e = 0; e < NE; ++e) red[t][e] += red[t + s][e];
    }
    __syncthreads();
  }
  if (t == 0) {
    float v1 = -1e30f; int e1 = 0;
#pragma unroll
    for (int e = 0; e < NE; ++e) { float v = red[0][e]; if (v > v1) { v1 = v; e1 = e; } }
    float v2 = -1e30f; int e2 = 0;
#pragma unroll
    for (int e = 0; e < NE; ++e) {
      if (e == e1) continue;
      float v = red[0][e]; if (v > v2) { v2 = v; e2 = e; }
    }
    float ev = expf(v2 - v1);
    eidx[b * 2] = e1;  eidx[b * 2 + 1] = e2;
    gval[b * 2] = 1.f / (1.f + ev);  gval[b * 2 + 1] = ev / (1.f + ev);
  }
}

// fused stats (aux loss, deterministic) + segment offsets + scatter
__global__ __launch_bounds__(TPB)
void stats_scatter(const int* __restrict__ eidx, const float* __restrict__ gval,
                   float* __restrict__ loss, int* __restrict__ seg_off,
                   int* __restrict__ seg_cnt, int* __restrict__ slot_token,
                   int* __restrict__ slot_of)
{
  const int t = threadIdx.x;
  float imp[NE] = {};
  int   cnt[NE] = {};
  for (int s = t; s < NSLOT; s += TPB) {
    int e = eidx[s]; float g = gval[s];
#pragma unroll
    for (int q = 0; q < NE; ++q) if (q == e) { imp[q] += g; cnt[q]++; }
  }
  __shared__ float rimp[TPB][NE];
  __shared__ int   rcnt[TPB][NE];
#pragma unroll
  for (int e = 0; e < NE; ++e) { rimp[t][e] = imp[e]; rcnt[t][e] = cnt[e]; }
  __syncthreads();
  for (int s = TPB / 2; s > 0; s >>= 1) {
    if (t < s) {
#pragma unroll
      for (int e = 0; e < NE; ++e) { rimp[t][e] += rimp[t + s][e]; rcnt[t][e] += rcnt[t + s][e]; }
    }
    __syncthreads();
  }
  __shared__ int s_off[NE], s_fill[NE];
  if (t == 0) {
    float mi = 0.f, ml = 0.f;
#pragma unroll
    for (int e = 0; e < NE; ++e) { mi += rimp[0][e]; ml += (float)rcnt[0][e]; }
    mi /= NE; ml /= NE;
    float vi = 0.f, vl = 0.f;
#pragma unroll
    for (int e = 0; e < NE; ++e) {
      float di = rimp[0][e] - mi; vi += di * di;
      float dl = (float)rcnt[0][e] - ml; vl += dl * dl;
    }
    vi /= (NE - 1); vl /= (NE - 1);   // ddof=1
    loss[0] += 0.01f * (vi / (mi * mi + 1e-10f) + vl / (ml * ml + 1e-10f));
    int off = 0;
#pragma unroll
    for (int e = 0; e < NE; ++e) {
      seg_off[e] = off; seg_cnt[e] = rcnt[0][e];
      s_off[e] = off; s_fill[e] = 0; off += rcnt[0][e];
    }
  }
  __syncthreads();
  for (int s = t; s < NSLOT; s += TPB) {
    int e = eidx[s];
    int pos = s_off[e] + atomicAdd(&s_fill[e], 1);
    slot_token[pos] = s >> 1;
    slot_of[s] = pos;
  }
}

// combine h[b] = g0*y[p0] + g1*y[p1] (split planes out), optionally fused with
// next layer's gating (logits computed from the in-register h row).
template<bool GATE>
__global__ __launch_bounds__(TPB)
void combine_gate(const float* __restrict__ y, const float* __restrict__ gv_in,
                  const int* __restrict__ slot_of, const float* __restrict__ w_gate,
                  u16* __restrict__ hh, u16* __restrict__ hl,
                  int* __restrict__ eidx, float* __restrict__ gval)
{
  const int b = blockIdx.x, t = threadIdx.x;
  const int p0 = slot_of[b * 2], p1 = slot_of[b * 2 + 1];
  const float g0 = gv_in[b * 2], g1 = gv_in[b * 2 + 1];
  float4 a = ((const float4*)(y + (size_t)p0 * HD))[t];
  float4 c = ((const float4*)(y + (size_t)p1 * HD))[t];
  float v[4] = { g0 * a.x + g1 * c.x, g0 * a.y + g1 * c.y,
                 g0 * a.z + g1 * c.z, g0 * a.w + g1 * c.w };
  ushort4 H, L;
  split2(v[0], H.x, L.x); split2(v[1], H.y, L.y);
  split2(v[2], H.z, L.z); split2(v[3], H.w, L.w);
  ((ushort4*)(hh + (size_t)b * HD))[t] = H;
  ((ushort4*)(hl + (size_t)b * HD))[t] = L;

  if (GATE) {
    float acc[NE] = {};
    const int i0 = t * 4;
#pragma unroll
    for (int j = 0; j < 4; ++j) {
      const float4* wg = (const float4*)(w_gate + (size_t)(i0 + j) * NE);
      float4 w0 = wg[0], w1 = wg[1];
      acc[0] = fmaf(v[j], w0.x, acc[0]); acc[1] = fmaf(v[j], w0.y, acc[1]);
      acc[2] = fmaf(v[j], w0.z, acc[2]); acc[3] = fmaf(v[j], w0.w, acc[3]);
      acc[4] = fmaf(v[j], w1.x, acc[4]); acc[5] = fmaf(v[j], w1.y, acc[5]);
      acc[6] = fmaf(v[j], w1.z, acc[6]); acc[7] = fmaf(v[j], w1.w, acc[7]);
    }
    __shared__ float red[TPB][NE];
#pragma unroll
    for (int e = 0; e < NE; ++e) red[t][e] = acc[e];
    __syncthreads();
    for (int s = TPB / 2; s > 0; s >>= 1) {
      if (t < s) {
#pragma unroll
        for (int e = 0; e < NE; ++e) red[t][e] += red[t + s][e];
      }
      __syncthreads();
    }
    if (t == 0) {
      float v1 = -1e30f; int e1 = 0;
#pragma unroll
      for (int e = 0; e < NE; ++e) { float vv = red[0][e]; if (vv > v1) { v1 = vv; e1 = e; } }
      float v2 = -1e30f; int e2 = 0;
#pragma unroll
      for (int e = 0; e < NE; ++e) {
        if (e == e1) continue;
        float vv = red[0][e]; if (vv > v2) { v2 = vv; e2 = e; }
      }
      float ev = expf(v2 - v1);
      eidx[b * 2] = e1;  eidx[b * 2 + 1] = e2;
      gval[b * 2] = 1.f / (1.f + ev);  gval[b * 2 + 1] = ev / (1.f + ev);
    }
  }
}

__global__ void init_kernel(float* loss) { loss[0] = 0.f; }
__global__ void write_loss(const float* __restrict__ loss, float* __restrict__ out)
{ out[0] = loss[0]; }

// =====================================================================
//          FALLBACK fp32 PATH (round-1, verified) — used if ws small
// =====================================================================
template<bool RELU, bool GROUPED, bool GATHER>
__global__ __launch_bounds__(TPB)
void gemm_f32(const float* __restrict__ A, const int* __restrict__ gatherIdx,
              const float* __restrict__ B, const float* __restrict__ bias,
              float* __restrict__ C, const int* __restrict__ seg_off,
              const int* __restrict__ seg_cnt, int M, int K, int N)
{
  const int e = GROUPED ? blockIdx.z : 0;
  int cnt = M, base = 0;
  if (GROUPED) { cnt = seg_cnt[e]; base = seg_off[e]; }
  const int tm = blockIdx.y, tn = blockIdx.x;
  if (tm * 64 >= cnt) return;
  const float* Bp = B + (size_t)e * K * N;
  const float* bp = bias + (size_t)e * N;
  __shared__ float As[16][68];
  __shared__ float Bs[16][64];
  const int t = threadIdx.x;
  const int rm0 = (t >> 4) << 2, cn0 = (t & 15) << 2;
  int arow[4]; bool aval[4];
#pragma unroll
  for (int i = 0; i < 4; ++i) {
    int idx = t + i * TPB;
    int r = idx >> 4;
    int row_in = tm * 64 + r;
    bool v = row_in < cnt;
    int src;
    if (GATHER) src = v ? gatherIdx[base + row_in] : 0;
    else        src = v ? (GROUPED ? base + row_in : row_in) : 0;
    arow[i] = src; aval[i] = v;
  }
  float acc[4][4] = {};
  for (int k0 = 0; k0 < K; k0 += 16) {
#pragma unroll
    for (int i = 0; i < 4; ++i) {
      int idx = t + i * TPB;
      int r = idx >> 4, kk = idx & 15;
      As[kk][r] = aval[i] ? A[(size_t)arow[i] * K + k0 + kk] : 0.f;
    }
#pragma unroll
    for (int i = 0; i < 4; ++i) {
      int idx = t + i * TPB;
      int kk = idx >> 6, n = idx & 63;
      Bs[kk][n] = Bp[(size_t)(k0 + kk) * N + tn * 64 + n];
    }
    __syncthreads();
#pragma unroll
    for (int kk = 0; kk < 16; ++kk) {
      const float4 a4 = *(const float4*)&As[kk][rm0];
      const float4 b4 = *(const float4*)&Bs[kk][cn0];
      float av[4] = {a4.x, a4.y, a4.z, a4.w};
      float bv[4] = {b4.x, b4.y, b4.z, b4.w};
#pragma unroll
      for (int i = 0; i < 4; ++i)
#pragma unroll
        for (int j = 0; j < 4; ++j) acc[i][j] = fmaf(av[i], bv[j], acc[i][j]);
    }
    __syncthreads();
  }
#pragma unroll
  for (int i = 0; i < 4; ++i) {
    int row_in = tm * 64 + rm0 + i;
    if (row_in >= cnt) continue;
    size_t orow = (size_t)(base + row_in);
    float v0 = acc[i][0] + bp[tn * 64 + cn0 + 0];
    float v1 = acc[i][1] + bp[tn * 64 + cn0 + 1];
    float v2 = acc[i][2] + bp[tn * 64 + cn0 + 2];
    float v3 = acc[i][3] + bp[tn * 64 + cn0 + 3];
    if (RELU) { v0 = fmaxf(v0, 0.f); v1 = fmaxf(v1, 0.f); v2 = fmaxf(v2, 0.f); v3 = fmaxf(v3, 0.f); }
    *(float4*)&C[orow * N + tn * 64 + cn0] = make_float4(v0, v1, v2, v3);
  }
}

__global__ __launch_bounds__(TPB)
void gate_f32(const float* __restrict__ h, const float* __restrict__ w_gate,
              int* __restrict__ eidx, float* __restrict__ gval)
{
  const int b = blockIdx.x, t = threadIdx.x;
  float acc[NE] = {};
  const float* hb = h + (size_t)b * HD;
  for (int i = t; i < HD; i += TPB) {
    float hv = hb[i];
    const float* wg = w_gate + (size_t)i * NE;
#pragma unroll
    for (int e = 0; e < NE; ++e) acc[e] = fmaf(hv, wg[e], acc[e]);
  }
  __shared__ float red[TPB][NE];
#pragma unroll
  for (int e = 0; e < NE; ++e) red[t][e] = acc[e];
  __syncthreads();
  for (int s = TPB / 2; s > 0; s >>= 1) {
    if (t < s) {
#pragma unroll
      for (int e = 0; e < NE; ++e) red[t][e] += red[t + s][e];
    }
    __syncthreads();
  }
  if (t == 0) {
    float v1 = -1e30f; int e1 = 0;
#pragma unroll
    for (int e = 0; e < NE; ++e) { float v = red[0][e]; if (v > v1) { v1 = v; e1 = e; } }
    float v2 = -1e30f; int e2 = 0;
#pragma unroll
    for (int e = 0; e < NE; ++e) {
      if (e == e1) continue;
      float v = red[0][e]; if (v > v2) { v2 = v; e2 = e; }
    }
    float ev = expf(v2 - v1);
    eidx[b * 2] = e1;  eidx[b * 2 + 1] = e2;
    gval[b * 2] = 1.f / (1.f + ev);  gval[b * 2 + 1] = ev / (1.f + ev);
  }
}

__global__ __launch_bounds__(TPB)
void combine_f32(const float* __restrict__ y, const float* __restrict__ gval,
                 const int* __restrict__ slot_of, float* __restrict__ h)
{
  const int b = blockIdx.x, t = threadIdx.x;
  const int p0 = slot_of[b * 2], p1 = slot_of[b * 2 + 1];
  const float g0 = gval[b * 2], g1 = gval[b * 2 + 1];
  const float4* y0 = (const float4*)(y + (size_t)p0 * HD);
  const float4* y1 = (const float4*)(y + (size_t)p1 * HD);
  float4* hb = (float4*)(h + (size_t)b * HD);
  for (int i = t; i < HD / 4; i += TPB) {
    float4 a = y0[i], c = y1[i];
    hb[i] = make_float4(g0 * a.x + g1 * c.x, g0 * a.y + g1 * c.y,
                        g0 * a.z + g1 * c.z, g0 * a.w + g1 * c.w);
  }
}

// =====================================================================

extern "C" void kernel_launch(void* const* d_in, const int* in_sizes, int n_in,
                              void* d_out, int out_size, void* d_ws, size_t ws_size,
                              hipStream_t stream)
{
  const float* x      = (const float*)d_in[0];
  const float* enc_w  = (const float*)d_in[1];
  const float* enc_b  = (const float*)d_in[2];
  const float* w_gate = (const float*)d_in[3];
  const float* w1     = (const float*)d_in[4];
  const float* b1     = (const float*)d_in[5];
  const float* w2     = (const float*)d_in[6];
  const float* b2     = (const float*)d_in[7];
  const float* dec_w  = (const float*)d_in[8];
  const float* dec_b  = (const float*)d_in[9];
  float* outp = (float*)d_out;
  dim3 blk(TPB);

  const size_t NEED = 120ull << 20;
  if (ws_size >= NEED) {
    // ---------------- split-bf16 MFMA path ----------------
    char* p = (char*)d_ws;
    auto alloc = [&](size_t bytes) { char* r = p; p += (bytes + 255) & ~(size_t)255; return r; };
    u16* w1t_h = (u16*)alloc((size_t)NE * HD * HD * 2);
    u16* w1t_l = (u16*)alloc((size_t)NE * HD * HD * 2);
    u16* w2t_h = (u16*)alloc((size_t)NE * HD * HD * 2);
    u16* w2t_l = (u16*)alloc((size_t)NE * HD * HD * 2);
    u16* ewt_h = (u16*)alloc((size_t)IND * HD * 2);
    u16* ewt_l = (u16*)alloc((size_t)IND * HD * 2);
    u16* dwt_h = (u16*)alloc((size_t)HD * OUTD * 2);
    u16* dwt_l = (u16*)alloc((size_t)HD * OUTD * 2);
    u16* x_h   = (u16*)alloc((size_t)NTOK * IND * 2);
    u16* x_l   = (u16*)alloc((size_t)NTOK * IND * 2);
    u16* h_h   = (u16*)alloc((size_t)NTOK * HD * 2);
    u16* h_l   = (u16*)alloc((size_t)NTOK * HD * 2);
    u16* hid_h = (u16*)alloc((size_t)NSLOT * HD * 2);
    u16* hid_l = (u16*)alloc((size_t)NSLOT * HD * 2);
    float* y   = (float*)alloc((size_t)NSLOT * HD * 4);
    float* Cp  = (float*)alloc((size_t)NSLOT * HD * 4);
    int*   cnt_arr    = (int*)alloc(4096 * 4);
    int*   eidx       = (int*)alloc(NSLOT * 4);
    float* gval       = (float*)alloc(NSLOT * 4);
    int*   slot_of    = (int*)alloc(NSLOT * 4);
    int*   slot_token = (int*)alloc(NSLOT * 4);
    int*   seg_off    = (int*)alloc(256);
    int*   seg_cnt    = (int*)alloc(256);
    float* loss       = (float*)alloc(256);

    init_kernel<<<1, 1, 0, stream>>>(loss);
    zero_scratch<<<NSLOT * HD / 4 / TPB, blk, 0, stream>>>((float4*)Cp, (int4*)cnt_arr);
    transpose_split<<<dim3(HD / 32, HD / 32, NE), blk, 0, stream>>>(w1, w1t_h, w1t_l, HD, HD);
    transpose_split<<<dim3(HD / 32, HD / 32, NE), blk, 0, stream>>>(w2, w2t_h, w2t_l, HD, HD);
    transpose_split<<<dim3(HD / 32, IND / 32, 1), blk, 0, stream>>>(enc_w, ewt_h, ewt_l, IND, HD);
    transpose_split<<<dim3(OUTD / 32, HD / 32, 1), blk, 0, stream>>>(dec_w, dwt_h, dwt_l, HD, OUTD);
    split_rows<<<(NTOK * IND / 4 + TPB - 1) / TPB, blk, 0, stream>>>(x, x_h, x_l, NTOK * IND);

    // encoder: h = relu(x @ enc_w + enc_b)  [split out, split-K=2]
    gemm_split<true, false, false, true><<<dim3(HD / 64, NTOK / 64, 2), blk, 0, stream>>>(
        x_h, x_l, nullptr, ewt_h, ewt_l, enc_b, nullptr, h_h, h_l, nullptr, nullptr,
        Cp, cnt_arr, NTOK, IND, HD);

    gate_split<<<NTOK, blk, 0, stream>>>(h_h, h_l, w_gate, eidx, gval);
    for (int L = 0; L < 10; ++L) {
      stats_scatter<<<1, blk, 0, stream>>>(eidx, gval, loss, seg_off, seg_cnt,
                                           slot_token, slot_of);
      gemm_split<true, true, true, true><<<dim3(HD / 64, NSLOT / 64, NE * 2), blk, 0, stream>>>(
          h_h, h_l, slot_token, w1t_h, w1t_l, b1, nullptr, hid_h, hid_l,
          seg_off, seg_cnt, Cp, cnt_arr, 0, HD, HD);
      gemm_split<false, true, false, false><<<dim3(HD / 64, NSLOT / 64, NE * 2), blk, 0, stream>>>(
          hid_h, hid_l, nullptr, w2t_h, w2t_l, b2, y, nullptr, nullptr,
          seg_off, seg_cnt, Cp, cnt_arr, 0, HD, HD);
      if (L < 9)
        combine_gate<true><<<NTOK, blk, 0, stream>>>(y, gval, slot_of, w_gate,
                                                     h_h, h_l, eidx, gval);
      else
        combine_gate<false><<<NTOK, blk, 0, stream>>>(y, gval, slot_of, w_gate,
                                                      h_h, h_l, eidx, gval);
    }

    // decoder: out = relu(h @ dec_w + dec_b)  [f32 out, split-K=2]
    gemm_split<true, false, false, false><<<dim3(OUTD / 64, NTOK / 64, 2), blk, 0, stream>>>(
        h_h, h_l, nullptr, dwt_h, dwt_l, dec_b, outp, nullptr, nullptr, nullptr, nullptr,
        Cp, cnt_arr, NTOK, HD, OUTD);
    write_loss<<<1, 1, 0, stream>>>(loss, outp + NTOK * OUTD);
    return;
  }

  // ---------------- fallback fp32 path (round-1, verified) ----------------
  char* ws = (char*)d_ws;
  float* h   = (float*)(ws);
  float* hid = (float*)(ws + (4u  << 20));
  float* y   = (float*)(ws + (12u << 20));
  char* sp = ws + (20u << 20);
  int*   eidx       = (int*)sp;    sp += NSLOT * 4;
  float* gval       = (float*)sp;  sp += NSLOT * 4;
  int*   slot_of    = (int*)sp;    sp += NSLOT * 4;
  int*   slot_token = (int*)sp;    sp += NSLOT * 4;
  int*   seg_off    = (int*)sp;    sp += 64;
  int*   seg_cnt    = (int*)sp;    sp += 64;
  float* loss       = (float*)sp;  sp += 64;

  init_kernel<<<1, 1, 0, stream>>>(loss);
  gemm_f32<true, false, false><<<dim3(HD / 64, NTOK / 64, 1), blk, 0, stream>>>(
      x, nullptr, enc_w, enc_b, h, nullptr, nullptr, NTOK, IND, HD);
  for (int L = 0; L < 10; ++L) {
    gate_f32<<<NTOK, blk, 0, stream>>>(h, w_gate, eidx, gval);
    stats_scatter<<<1, blk, 0, stream>>>(eidx, gval, loss, seg_off, seg_cnt,
                                         slot_token, slot_of);
    gemm_f32<true, true, true><<<dim3(HD / 64, NTOK / 64, NE), blk, 0, stream>>>(
        h, slot_token, w1, b1, hid, seg_off, seg_cnt, 0, HD, HD);
    gemm_f32<false, true, false><<<dim3(HD / 64, NTOK / 64, NE), blk, 0, stream>>>(
        hid, nullptr, w2, b2, y, seg_off, seg_cnt, 0, HD, HD);
    combine_f32<<<NTOK, blk, 0, stream>>>(y, gval, slot_of, h);
  }
  gemm_f32<true, false, false><<<dim3(OUTD / 64, NTOK / 64, 1), blk, 0, stream>>>(
      h, nullptr, dec_w, dec_b, outp, nullptr, nullptr, NTOK, HD, OUTD);
  write_loss<<<1, 1, 0, stream>>>(loss, outp + NTOK * OUTD);
}

// Round 9
// 763.675 us; speedup vs baseline: 6.4141x; 6.4141x over previous
//
#include <hip/hip_runtime.h>
#include <math.h>

#define TPB 256
typedef unsigned short u16;
typedef unsigned int u32;
typedef __bf16 bf16x8 __attribute__((ext_vector_type(8)));
typedef float f32x4 __attribute__((ext_vector_type(4)));

namespace {
constexpr int NTOK  = 1024;
constexpr int IND   = 512;
constexpr int HD    = 1024;
constexpr int OUTD  = 512;
constexpr int NE    = 8;
constexpr int NSLOT = 2048;
}

// ---------------- bf16 split helpers (RNE) ----------------
__device__ __forceinline__ u16 f2bf(float f) {
  u32 x = __float_as_uint(f);
  x += 0x7fffu + ((x >> 16) & 1u);
  return (u16)(x >> 16);
}
__device__ __forceinline__ float bf2f(u16 u) { return __uint_as_float(((u32)u) << 16); }
__device__ __forceinline__ void split2(float v, u16& h, u16& l) {
  h = f2bf(v);
  l = f2bf(v - bf2f(h));
}

__device__ __forceinline__ void gll16(const void* g, void* l) {
  __builtin_amdgcn_global_load_lds((const __attribute__((address_space(1))) void*)g,
                                   (__attribute__((address_space(3))) void*)l, 16, 0, 0);
}

// =====================================================================
//                       SPLIT-BF16 MFMA PATH
// =====================================================================

// transpose + split + TILE-PACK (BN=64): in[z][K][N] f32 -> packed B planes.
// Tile (nb = n>>6, ks = k>>6) is 4096 u16 contiguous; element (n,k) at
// tile*4096 + ((n&63)*8 + (((k>>3)&7) ^ (n&7)))*8 + (k&7)  — exactly the
// GEMM staging slot order (XOR swizzle baked in).
__global__ __launch_bounds__(TPB)
void transpose_split(const float* __restrict__ in, u16* __restrict__ ohi,
                     u16* __restrict__ olo, int K, int N)
{
  const int z = blockIdx.z;
  in  += (size_t)z * K * N;
  ohi += (size_t)z * K * N;
  olo += (size_t)z * K * N;
  __shared__ float tile[32][33];
  const int k0 = blockIdx.y * 32, n0 = blockIdx.x * 32;
  const int tx = threadIdx.x & 31, ty = threadIdx.x >> 5;
#pragma unroll
  for (int i = 0; i < 4; ++i) {
    int k = ty + i * 8;
    tile[k][tx] = in[(size_t)(k0 + k) * N + n0 + tx];
  }
  __syncthreads();
#pragma unroll
  for (int i = 0; i < 4; ++i) {
    int n = ty + i * 8;
    float v = tile[tx][n];                 // element (k = k0+tx, n = n0+n)
    u16 h, l; split2(v, h, l);
    int kk = k0 + tx, nn = n0 + n;
    size_t o = ((size_t)((nn >> 6) * (K >> 6) + (kk >> 6)) << 12)
             + (((nn & 63) * 8 + (((kk >> 3) & 7) ^ (nn & 7))) << 3) + (kk & 7);
    ohi[o] = h; olo[o] = l;
  }
}

// row split (no transpose): in[M][K] f32 -> hi/lo bf16 same layout
__global__ __launch_bounds__(TPB)
void split_rows(const float* __restrict__ in, u16* __restrict__ oh,
                u16* __restrict__ ol, int nelem)
{
  int i = blockIdx.x * TPB + threadIdx.x;
  if (i * 4 >= nelem) return;
  float4 v = ((const float4*)in)[i];
  ushort4 H, L;
  split2(v.x, H.x, L.x); split2(v.y, H.y, L.y);
  split2(v.z, H.z, L.z); split2(v.w, H.w, L.w);
  ((ushort4*)oh)[i] = H;
  ((ushort4*)ol)[i] = L;
}

// Split-bf16 MFMA GEMM: C = act(A@B + bias). BM=64 BN=64 BK=64,
// 4 waves (2x2), wave tile 32x32, 3 MFMAs per frag pair.
// 2 x 32KB LDS double buffer (64KB -> 2 blocks/CU co-resident) WITH counted
// vmcnt(8): each block's next-stage 32KB stays in flight across the barrier
// while its partner block computes — pipeline depth (r3/r4 machinery) AND
// inter-block TLP (r7) combined.
// Schedule/iter: barrier; stage(next); vmcnt(8); barrier; compute(cur).
template<bool RELU, bool GROUPED, bool GATHER, bool SPLIT_OUT>
__global__ __launch_bounds__(TPB)
void gemm_split(const u16* __restrict__ Ah, const u16* __restrict__ Al,
                const int* __restrict__ gatherIdx,
                const u16* __restrict__ Bh, const u16* __restrict__ Bl,
                const float* __restrict__ bias,
                float* __restrict__ Cf, u16* __restrict__ Ch, u16* __restrict__ Cl,
                const int* __restrict__ seg_off, const int* __restrict__ seg_cnt,
                int M, int K, int N)
{
  const int e = GROUPED ? blockIdx.z : 0;
  int cnt = M, base = 0;
  if (GROUPED) { cnt = seg_cnt[e]; base = seg_off[e]; }
  const int tm = blockIdx.y, tn = blockIdx.x;
  if (tm * 64 >= cnt) return;

  // 2 buffers x 16384 u16 (AH 4096 | AL 4096 | BH 4096 | BL 4096) = 64KB
  __shared__ u16 smem[32768];
  constexpr int AHo = 0, ALo = 4096, BHo = 8192, BLo = 12288, BUF = 16384;

  const int t = threadIdx.x;
  const int wid = t >> 6, lane = t & 63;
  const int wr = wid >> 1, wc = wid & 1;   // 2x2 wave grid, wave tile 32x32

  // A staging: row-major source, swizzled k-block; 2 slots/thread
  const u16* aph[2]; const u16* apl[2];
#pragma unroll
  for (int i = 0; i < 2; ++i) {
    int slot = t + i * TPB;
    int row = slot >> 3, kblk = slot & 7;
    int kbs = kblk ^ (row & 7);
    int row_in = tm * 64 + row;
    int rv = row_in < cnt ? row_in : 0;
    int src;
    if (GATHER)      src = gatherIdx[base + rv];
    else             src = GROUPED ? base + rv : rv;
    size_t off = (size_t)src * K + kbs * 8;
    aph[i] = Ah + off; apl[i] = Al + off;
  }
  // B staging: tile-packed source — slot-linear contiguous.
  const u16* bsh; const u16* bsl;
  {
    size_t pb = ((size_t)((GROUPED ? e : 0) * (N >> 6) + tn) * (K >> 6)) << 12;
    bsh = Bh + pb; bsl = Bl + pb;
  }

  auto stage = [&](int bb, int ks) {   // 8 gll16/thread = 32KB total
#pragma unroll
    for (int i = 0; i < 2; ++i) {
      int so = (t + i * TPB) * 8;
      gll16(aph[i] + (ks << 6), &smem[bb + AHo + so]);
      gll16(apl[i] + (ks << 6), &smem[bb + ALo + so]);
    }
    const size_t tb = (size_t)ks << 12;
#pragma unroll
    for (int i = 0; i < 2; ++i) {
      int so = (t + i * TPB) * 8;
      gll16(bsh + tb + so, &smem[bb + BHo + so]);
      gll16(bsl + tb + so, &smem[bb + BLo + so]);
    }
  };

  f32x4 acc[2][2];
#pragma unroll
  for (int i = 0; i < 2; ++i)
#pragma unroll
    for (int j = 0; j < 2; ++j) acc[i][j] = (f32x4){0.f, 0.f, 0.f, 0.f};

  auto compute = [&](int bb) {
#pragma unroll
    for (int s = 0; s < 2; ++s) {
      const int kb = s * 4 + (lane >> 4);
      bf16x8 fah[2], fal[2];
#pragma unroll
      for (int fr = 0; fr < 2; ++fr) {
        int ar = wr * 32 + fr * 16 + (lane & 15);
        int off = bb + ar * 64 + ((kb ^ (ar & 7)) << 3);
        fah[fr] = *(const bf16x8*)&smem[AHo + off];
        fal[fr] = *(const bf16x8*)&smem[ALo + off];
      }
      bf16x8 fbh[2], fbl[2];
#pragma unroll
      for (int fc = 0; fc < 2; ++fc) {
        int bn = wc * 32 + fc * 16 + (lane & 15);
        int off = bb + bn * 64 + ((kb ^ (bn & 7)) << 3);
        fbh[fc] = *(const bf16x8*)&smem[BHo + off];
        fbl[fc] = *(const bf16x8*)&smem[BLo + off];
      }
      __builtin_amdgcn_s_setprio(1);
#pragma unroll
      for (int fr = 0; fr < 2; ++fr)
#pragma unroll
        for (int fc = 0; fc < 2; ++fc) {
          acc[fr][fc] = __builtin_amdgcn_mfma_f32_16x16x32_bf16(fah[fr], fbh[fc], acc[fr][fc], 0, 0, 0);
          acc[fr][fc] = __builtin_amdgcn_mfma_f32_16x16x32_bf16(fah[fr], fbl[fc], acc[fr][fc], 0, 0, 0);
          acc[fr][fc] = __builtin_amdgcn_mfma_f32_16x16x32_bf16(fal[fr], fbh[fc], acc[fr][fc], 0, 0, 0);
        }
      __builtin_amdgcn_s_setprio(0);
    }
  };

  // Double-buffered K-loop with counted vmcnt:
  //   barrier          — partner-safe: everyone done reading buf being staged
  //   stage(next)      — 8 loads issued, stay in flight across compute
  //   vmcnt(8)         — drains ONLY the previous stage (oldest 8)
  //   barrier          — its data now visible to all waves
  //   compute(cur)
  const int NT = K >> 6;
  int buf = 0;
  stage(0, 0);
  for (int tt = 0; tt < NT; ++tt) {
    __builtin_amdgcn_s_barrier();
    if (tt + 1 < NT) {
      stage((buf ^ 1) * BUF, tt + 1);
      asm volatile("s_waitcnt vmcnt(8)" ::: "memory");
    } else {
      asm volatile("s_waitcnt vmcnt(0)" ::: "memory");
    }
    __builtin_amdgcn_s_barrier();
    compute(buf * BUF);
    buf ^= 1;
  }

  const float* bp = bias + (GROUPED ? (size_t)e * N : 0);
#pragma unroll
  for (int fr = 0; fr < 2; ++fr) {
#pragma unroll
    for (int q = 0; q < 4; ++q) {
      int row_in = tm * 64 + wr * 32 + fr * 16 + ((lane >> 4) << 2) + q;
      if (row_in >= cnt) continue;
      size_t orow = (size_t)(GROUPED ? base + row_in : row_in);
#pragma unroll
      for (int fc = 0; fc < 2; ++fc) {
        int col = tn * 64 + wc * 32 + fc * 16 + (lane & 15);
        float v = acc[fr][fc][q] + bp[col];
        if (RELU) v = fmaxf(v, 0.f);
        if (SPLIT_OUT) {
          u16 h, l; split2(v, h, l);
          Ch[orow * N + col] = h;
          Cl[orow * N + col] = l;
        } else {
          Cf[orow * N + col] = v;
        }
      }
    }
  }
}

// layer-0 gating: logits = (hi+lo) @ w_gate, stable top-2 + softmax (vectorized)
__global__ __launch_bounds__(TPB)
void gate_split(const u16* __restrict__ hh, const u16* __restrict__ hl,
                const float* __restrict__ w_gate,
                int* __restrict__ eidx, float* __restrict__ gval)
{
  const int b = blockIdx.x, t = threadIdx.x;
  ushort4 H = ((const ushort4*)(hh + (size_t)b * HD))[t];
  ushort4 L = ((const ushort4*)(hl + (size_t)b * HD))[t];
  float hv[4] = { bf2f(H.x) + bf2f(L.x), bf2f(H.y) + bf2f(L.y),
                  bf2f(H.z) + bf2f(L.z), bf2f(H.w) + bf2f(L.w) };
  float acc[NE] = {};
  const int i0 = t * 4;
#pragma unroll
  for (int j = 0; j < 4; ++j) {
    const float4* wg = (const float4*)(w_gate + (size_t)(i0 + j) * NE);
    float4 w0 = wg[0], w1 = wg[1];
    acc[0] = fmaf(hv[j], w0.x, acc[0]); acc[1] = fmaf(hv[j], w0.y, acc[1]);
    acc[2] = fmaf(hv[j], w0.z, acc[2]); acc[3] = fmaf(hv[j], w0.w, acc[3]);
    acc[4] = fmaf(hv[j], w1.x, acc[4]); acc[5] = fmaf(hv[j], w1.y, acc[5]);
    acc[6] = fmaf(hv[j], w1.z, acc[6]); acc[7] = fmaf(hv[j], w1.w, acc[7]);
  }
  __shared__ float red[TPB][NE];
#pragma unroll
  for (int e = 0; e < NE; ++e) red[t][e] = acc[e];
  __syncthreads();
  for (int s = TPB / 2; s > 0; s >>= 1) {
    if (t < s) {
#pragma unroll
      for (int e = 0; e < NE; ++e) red[t][e] += red[t + s][e];
    }
    __syncthreads();
  }
  if (t == 0) {
    float v1 = -1e30f; int e1 = 0;
#pragma unroll
    for (int e = 0; e < NE; ++e) { float v = red[0][e]; if (v > v1) { v1 = v; e1 = e; } }
    float v2 = -1e30f; int e2 = 0;
#pragma unroll
    for (int e = 0; e < NE; ++e) {
      if (e == e1) continue;
      float v = red[0][e]; if (v > v2) { v2 = v; e2 = e; }
    }
    float ev = expf(v2 - v1);
    eidx[b * 2] = e1;  eidx[b * 2 + 1] = e2;
    gval[b * 2] = 1.f / (1.f + ev);  gval[b * 2 + 1] = ev / (1.f + ev);
  }
}

// fused stats (aux loss, deterministic) + segment offsets + scatter
__global__ __launch_bounds__(TPB)
void stats_scatter(const int* __restrict__ eidx, const float* __restrict__ gval,
                   float* __restrict__ loss, int* __restrict__ seg_off,
                   int* __restrict__ seg_cnt, int* __restrict__ slot_token,
                   int* __restrict__ slot_of)
{
  const int t = threadIdx.x;
  float imp[NE] = {};
  int   cnt[NE] = {};
  for (int s = t; s < NSLOT; s += TPB) {
    int e = eidx[s]; float g = gval[s];
#pragma unroll
    for (int q = 0; q < NE; ++q) if (q == e) { imp[q] += g; cnt[q]++; }
  }
  __shared__ float rimp[TPB][NE];
  __shared__ int   rcnt[TPB][NE];
#pragma unroll
  for (int e = 0; e < NE; ++e) { rimp[t][e] = imp[e]; rcnt[t][e] = cnt[e]; }
  __syncthreads();
  for (int s = TPB / 2; s > 0; s >>= 1) {
    if (t < s) {
#pragma unroll
      for (int e = 0; e < NE; ++e) { rimp[t][e] += rimp[t + s][e]; rcnt[t][e] += rcnt[t + s][e]; }
    }
    __syncthreads();
  }
  __shared__ int s_off[NE], s_fill[NE];
  if (t == 0) {
    float mi = 0.f, ml = 0.f;
#pragma unroll
    for (int e = 0; e < NE; ++e) { mi += rimp[0][e]; ml += (float)rcnt[0][e]; }
    mi /= NE; ml /= NE;
    float vi = 0.f, vl = 0.f;
#pragma unroll
    for (int e = 0; e < NE; ++e) {
      float di = rimp[0][e] - mi; vi += di * di;
      float dl = (float)rcnt[0][e] - ml; vl += dl * dl;
    }
    vi /= (NE - 1); vl /= (NE - 1);   // ddof=1
    loss[0] += 0.01f * (vi / (mi * mi + 1e-10f) + vl / (ml * ml + 1e-10f));
    int off = 0;
#pragma unroll
    for (int e = 0; e < NE; ++e) {
      seg_off[e] = off; seg_cnt[e] = rcnt[0][e];
      s_off[e] = off; s_fill[e] = 0; off += rcnt[0][e];
    }
  }
  __syncthreads();
  for (int s = t; s < NSLOT; s += TPB) {
    int e = eidx[s];
    int pos = s_off[e] + atomicAdd(&s_fill[e], 1);
    slot_token[pos] = s >> 1;
    slot_of[s] = pos;
  }
}

// combine h[b] = g0*y[p0] + g1*y[p1] (split planes out), optionally fused with
// next layer's gating (logits computed from the in-register h row).
template<bool GATE>
__global__ __launch_bounds__(TPB)
void combine_gate(const float* __restrict__ y, const float* __restrict__ gv_in,
                  const int* __restrict__ slot_of, const float* __restrict__ w_gate,
                  u16* __restrict__ hh, u16* __restrict__ hl,
                  int* __restrict__ eidx, float* __restrict__ gval)
{
  const int b = blockIdx.x, t = threadIdx.x;
  const int p0 = slot_of[b * 2], p1 = slot_of[b * 2 + 1];
  const float g0 = gv_in[b * 2], g1 = gv_in[b * 2 + 1];
  float4 a = ((const float4*)(y + (size_t)p0 * HD))[t];
  float4 c = ((const float4*)(y + (size_t)p1 * HD))[t];
  float v[4] = { g0 * a.x + g1 * c.x, g0 * a.y + g1 * c.y,
                 g0 * a.z + g1 * c.z, g0 * a.w + g1 * c.w };
  ushort4 H, L;
  split2(v[0], H.x, L.x); split2(v[1], H.y, L.y);
  split2(v[2], H.z, L.z); split2(v[3], H.w, L.w);
  ((ushort4*)(hh + (size_t)b * HD))[t] = H;
  ((ushort4*)(hl + (size_t)b * HD))[t] = L;

  if (GATE) {
    float acc[NE] = {};
    const int i0 = t * 4;
#pragma unroll
    for (int j = 0; j < 4; ++j) {
      const float4* wg = (const float4*)(w_gate + (size_t)(i0 + j) * NE);
      float4 w0 = wg[0], w1 = wg[1];
      acc[0] = fmaf(v[j], w0.x, acc[0]); acc[1] = fmaf(v[j], w0.y, acc[1]);
      acc[2] = fmaf(v[j], w0.z, acc[2]); acc[3] = fmaf(v[j], w0.w, acc[3]);
      acc[4] = fmaf(v[j], w1.x, acc[4]); acc[5] = fmaf(v[j], w1.y, acc[5]);
      acc[6] = fmaf(v[j], w1.z, acc[6]); acc[7] = fmaf(v[j], w1.w, acc[7]);
    }
    __shared__ float red[TPB][NE];
#pragma unroll
    for (int e = 0; e < NE; ++e) red[t][e] = acc[e];
    __syncthreads();
    for (int s = TPB / 2; s > 0; s >>= 1) {
      if (t < s) {
#pragma unroll
        for (int e = 0; e < NE; ++e) red[t][e] += red[t + s][e];
      }
      __syncthreads();
    }
    if (t == 0) {
      float v1 = -1e30f; int e1 = 0;
#pragma unroll
      for (int e = 0; e < NE; ++e) { float vv = red[0][e]; if (vv > v1) { v1 = vv; e1 = e; } }
      float v2 = -1e30f; int e2 = 0;
#pragma unroll
      for (int e = 0; e < NE; ++e) {
        if (e == e1) continue;
        float vv = red[0][e]; if (vv > v2) { v2 = vv; e2 = e; }
      }
      float ev = expf(v2 - v1);
      eidx[b * 2] = e1;  eidx[b * 2 + 1] = e2;
      gval[b * 2] = 1.f / (1.f + ev);  gval[b * 2 + 1] = ev / (1.f + ev);
    }
  }
}

__global__ void init_kernel(float* loss) { loss[0] = 0.f; }
__global__ void write_loss(const float* __restrict__ loss, float* __restrict__ out)
{ out[0] = loss[0]; }

// =====================================================================
//          FALLBACK fp32 PATH (round-1, verified) — used if ws small
// =====================================================================
template<bool RELU, bool GROUPED, bool GATHER>
__global__ __launch_bounds__(TPB)
void gemm_f32(const float* __restrict__ A, const int* __restrict__ gatherIdx,
              const float* __restrict__ B, const float* __restrict__ bias,
              float* __restrict__ C, const int* __restrict__ seg_off,
              const int* __restrict__ seg_cnt, int M, int K, int N)
{
  const int e = GROUPED ? blockIdx.z : 0;
  int cnt = M, base = 0;
  if (GROUPED) { cnt = seg_cnt[e]; base = seg_off[e]; }
  const int tm = blockIdx.y, tn = blockIdx.x;
  if (tm * 64 >= cnt) return;
  const float* Bp = B + (size_t)e * K * N;
  const float* bp = bias + (size_t)e * N;
  __shared__ float As[16][68];
  __shared__ float Bs[16][64];
  const int t = threadIdx.x;
  const int rm0 = (t >> 4) << 2, cn0 = (t & 15) << 2;
  int arow[4]; bool aval[4];
#pragma unroll
  for (int i = 0; i < 4; ++i) {
    int idx = t + i * TPB;
    int r = idx >> 4;
    int row_in = tm * 64 + r;
    bool v = row_in < cnt;
    int src;
    if (GATHER) src = v ? gatherIdx[base + row_in] : 0;
    else        src = v ? (GROUPED ? base + row_in : row_in) : 0;
    arow[i] = src; aval[i] = v;
  }
  float acc[4][4] = {};
  for (int k0 = 0; k0 < K; k0 += 16) {
#pragma unroll
    for (int i = 0; i < 4; ++i) {
      int idx = t + i * TPB;
      int r = idx >> 4, kk = idx & 15;
      As[kk][r] = aval[i] ? A[(size_t)arow[i] * K + k0 + kk] : 0.f;
    }
#pragma unroll
    for (int i = 0; i < 4; ++i) {
      int idx = t + i * TPB;
      int kk = idx >> 6, n = idx & 63;
      Bs[kk][n] = Bp[(size_t)(k0 + kk) * N + tn * 64 + n];
    }
    __syncthreads();
#pragma unroll
    for (int kk = 0; kk < 16; ++kk) {
      const float4 a4 = *(const float4*)&As[kk][rm0];
      const float4 b4 = *(const float4*)&Bs[kk][cn0];
      float av[4] = {a4.x, a4.y, a4.z, a4.w};
      float bv[4] = {b4.x, b4.y, b4.z, b4.w};
#pragma unroll
      for (int i = 0; i < 4; ++i)
#pragma unroll
        for (int j = 0; j < 4; ++j) acc[i][j] = fmaf(av[i], bv[j], acc[i][j]);
    }
    __syncthreads();
  }
#pragma unroll
  for (int i = 0; i < 4; ++i) {
    int row_in = tm * 64 + rm0 + i;
    if (row_in >= cnt) continue;
    size_t orow = (size_t)(base + row_in);
    float v0 = acc[i][0] + bp[tn * 64 + cn0 + 0];
    float v1 = acc[i][1] + bp[tn * 64 + cn0 + 1];
    float v2 = acc[i][2] + bp[tn * 64 + cn0 + 2];
    float v3 = acc[i][3] + bp[tn * 64 + cn0 + 3];
    if (RELU) { v0 = fmaxf(v0, 0.f); v1 = fmaxf(v1, 0.f); v2 = fmaxf(v2, 0.f); v3 = fmaxf(v3, 0.f); }
    *(float4*)&C[orow * N + tn * 64 + cn0] = make_float4(v0, v1, v2, v3);
  }
}

__global__ __launch_bounds__(TPB)
void gate_f32(const float* __restrict__ h, const float* __restrict__ w_gate,
              int* __restrict__ eidx, float* __restrict__ gval)
{
  const int b = blockIdx.x, t = threadIdx.x;
  float acc[NE] = {};
  const float* hb = h + (size_t)b * HD;
  for (int i = t; i < HD; i += TPB) {
    float hv = hb[i];
    const float* wg = w_gate + (size_t)i * NE;
#pragma unroll
    for (int e = 0; e < NE; ++e) acc[e] = fmaf(hv, wg[e], acc[e]);
  }
  __shared__ float red[TPB][NE];
#pragma unroll
  for (int e = 0; e < NE; ++e) red[t][e] = acc[e];
  __syncthreads();
  for (int s = TPB / 2; s > 0; s >>= 1) {
    if (t < s) {
#pragma unroll
      for (int e = 0; e < NE; ++e) red[t][e] += red[t + s][e];
    }
    __syncthreads();
  }
  if (t == 0) {
    float v1 = -1e30f; int e1 = 0;
#pragma unroll
    for (int e = 0; e < NE; ++e) { float v = red[0][e]; if (v > v1) { v1 = v; e1 = e; } }
    float v2 = -1e30f; int e2 = 0;
#pragma unroll
    for (int e = 0; e < NE; ++e) {
      if (e == e1) continue;
      float v = red[0][e]; if (v > v2) { v2 = v; e2 = e; }
    }
    float ev = expf(v2 - v1);
    eidx[b * 2] = e1;  eidx[b * 2 + 1] = e2;
    gval[b * 2] = 1.f / (1.f + ev);  gval[b * 2 + 1] = ev / (1.f + ev);
  }
}

__global__ __launch_bounds__(TPB)
void combine_f32(const float* __restrict__ y, const float* __restrict__ gval,
                 const int* __restrict__ slot_of, float* __restrict__ h)
{
  const int b = blockIdx.x, t = threadIdx.x;
  const int p0 = slot_of[b * 2], p1 = slot_of[b * 2 + 1];
  const float g0 = gval[b * 2], g1 = gval[b * 2 + 1];
  const float4* y0 = (const float4*)(y + (size_t)p0 * HD);
  const float4* y1 = (const float4*)(y + (size_t)p1 * HD);
  float4* hb = (float4*)(h + (size_t)b * HD);
  for (int i = t; i < HD / 4; i += TPB) {
    float4 a = y0[i], c = y1[i];
    hb[i] = make_float4(g0 * a.x + g1 * c.x, g0 * a.y + g1 * c.y,
                        g0 * a.z + g1 * c.z, g0 * a.w + g1 * c.w);
  }
}

// =====================================================================

extern "C" void kernel_launch(void* const* d_in, const int* in_sizes, int n_in,
                              void* d_out, int out_size, void* d_ws, size_t ws_size,
                              hipStream_t stream)
{
  const float* x      = (const float*)d_in[0];
  const float* enc_w  = (const float*)d_in[1];
  const float* enc_b  = (const float*)d_in[2];
  const float* w_gate = (const float*)d_in[3];
  const float* w1     = (const float*)d_in[4];
  const float* b1     = (const float*)d_in[5];
  const float* w2     = (const float*)d_in[6];
  const float* b2     = (const float*)d_in[7];
  const float* dec_w  = (const float*)d_in[8];
  const float* dec_b  = (const float*)d_in[9];
  float* outp = (float*)d_out;
  dim3 blk(TPB);

  const size_t NEED = 100ull << 20;
  if (ws_size >= NEED) {
    // ---------------- split-bf16 MFMA path ----------------
    char* p = (char*)d_ws;
    auto alloc = [&](size_t bytes) { char* r = p; p += (bytes + 255) & ~(size_t)255; return r; };
    u16* w1t_h = (u16*)alloc((size_t)NE * HD * HD * 2);
    u16* w1t_l = (u16*)alloc((size_t)NE * HD * HD * 2);
    u16* w2t_h = (u16*)alloc((size_t)NE * HD * HD * 2);
    u16* w2t_l = (u16*)alloc((size_t)NE * HD * HD * 2);
    u16* ewt_h = (u16*)alloc((size_t)IND * HD * 2);
    u16* ewt_l = (u16*)alloc((size_t)IND * HD * 2);
    u16* dwt_h = (u16*)alloc((size_t)HD * OUTD * 2);
    u16* dwt_l = (u16*)alloc((size_t)HD * OUTD * 2);
    u16* x_h   = (u16*)alloc((size_t)NTOK * IND * 2);
    u16* x_l   = (u16*)alloc((size_t)NTOK * IND * 2);
    u16* h_h   = (u16*)alloc((size_t)NTOK * HD * 2);
    u16* h_l   = (u16*)alloc((size_t)NTOK * HD * 2);
    u16* hid_h = (u16*)alloc((size_t)NSLOT * HD * 2);
    u16* hid_l = (u16*)alloc((size_t)NSLOT * HD * 2);
    float* y   = (float*)alloc((size_t)NSLOT * HD * 4);
    int*   eidx       = (int*)alloc(NSLOT * 4);
    float* gval       = (float*)alloc(NSLOT * 4);
    int*   slot_of    = (int*)alloc(NSLOT * 4);
    int*   slot_token = (int*)alloc(NSLOT * 4);
    int*   seg_off    = (int*)alloc(256);
    int*   seg_cnt    = (int*)alloc(256);
    float* loss       = (float*)alloc(256);

    init_kernel<<<1, 1, 0, stream>>>(loss);
    transpose_split<<<dim3(HD / 32, HD / 32, NE), blk, 0, stream>>>(w1, w1t_h, w1t_l, HD, HD);
    transpose_split<<<dim3(HD / 32, HD / 32, NE), blk, 0, stream>>>(w2, w2t_h, w2t_l, HD, HD);
    transpose_split<<<dim3(HD / 32, IND / 32, 1), blk, 0, stream>>>(enc_w, ewt_h, ewt_l, IND, HD);
    transpose_split<<<dim3(OUTD / 32, HD / 32, 1), blk, 0, stream>>>(dec_w, dwt_h, dwt_l, HD, OUTD);
    split_rows<<<(NTOK * IND / 4 + TPB - 1) / TPB, blk, 0, stream>>>(x, x_h, x_l, NTOK * IND);

    // encoder: h = relu(x @ enc_w + enc_b)  [split out]
    gemm_split<true, false, false, true><<<dim3(HD / 64, NTOK / 64, 1), blk, 0, stream>>>(
        x_h, x_l, nullptr, ewt_h, ewt_l, enc_b, nullptr, h_h, h_l, nullptr, nullptr,
        NTOK, IND, HD);

    gate_split<<<NTOK, blk, 0, stream>>>(h_h, h_l, w_gate, eidx, gval);
    for (int L = 0; L < 10; ++L) {
      stats_scatter<<<1, blk, 0, stream>>>(eidx, gval, loss, seg_off, seg_cnt,
                                           slot_token, slot_of);
      gemm_split<true, true, true, true><<<dim3(HD / 64, NSLOT / 64, NE), blk, 0, stream>>>(
          h_h, h_l, slot_token, w1t_h, w1t_l, b1, nullptr, hid_h, hid_l,
          seg_off, seg_cnt, 0, HD, HD);
      gemm_split<false, true, false, false><<<dim3(HD / 64, NSLOT / 64, NE), blk, 0, stream>>>(
          hid_h, hid_l, nullptr, w2t_h, w2t_l, b2, y, nullptr, nullptr,
          seg_off, seg_cnt, 0, HD, HD);
      if (L < 9)
        combine_gate<true><<<NTOK, blk, 0, stream>>>(y, gval, slot_of, w_gate,
                                                     h_h, h_l, eidx, gval);
      else
        combine_gate<false><<<NTOK, blk, 0, stream>>>(y, gval, slot_of, w_gate,
                                                      h_h, h_l, eidx, gval);
    }

    // decoder: out = relu(h @ dec_w + dec_b)  [f32 out]
    gemm_split<true, false, false, false><<<dim3(OUTD / 64, NTOK / 64, 1), blk, 0, stream>>>(
        h_h, h_l, nullptr, dwt_h, dwt_l, dec_b, outp, nullptr, nullptr, nullptr, nullptr,
        NTOK, HD, OUTD);
    write_loss<<<1, 1, 0, stream>>>(loss, outp + NTOK * OUTD);
    return;
  }

  // ---------------- fallback fp32 path (round-1, verified) ----------------
  char* ws = (char*)d_ws;
  float* h   = (float*)(ws);
  float* hid = (float*)(ws + (4u  << 20));
  float* y   = (float*)(ws + (12u << 20));
  char* sp = ws + (20u << 20);
  int*   eidx       = (int*)sp;    sp += NSLOT * 4;
  float* gval       = (float*)sp;  sp += NSLOT * 4;
  int*   slot_of    = (int*)sp;    sp += NSLOT * 4;
  int*   slot_token = (int*)sp;    sp += NSLOT * 4;
  int*   seg_off    = (int*)sp;    sp += 64;
  int*   seg_cnt    = (int*)sp;    sp += 64;
  float* loss       = (float*)sp;  sp += 64;

  init_kernel<<<1, 1, 0, stream>>>(loss);
  gemm_f32<true, false, false><<<dim3(HD / 64, NTOK / 64, 1), blk, 0, stream>>>(
      x, nullptr, enc_w, enc_b, h, nullptr, nullptr, NTOK, IND, HD);
  for (int L = 0; L < 10; ++L) {
    gate_f32<<<NTOK, blk, 0, stream>>>(h, w_gate, eidx, gval);
    stats_scatter<<<1, blk, 0, stream>>>(eidx, gval, loss, seg_off, seg_cnt,
                                         slot_token, slot_of);
    gemm_f32<true, true, true><<<dim3(HD / 64, NTOK / 64, NE), blk, 0, stream>>>(
        h, slot_token, w1, b1, hid, seg_off, seg_cnt, 0, HD, HD);
    gemm_f32<false, true, false><<<dim3(HD / 64, NTOK / 64, NE), blk, 0, stream>>>(
        hid, nullptr, w2, b2, y, seg_off, seg_cnt, 0, HD, HD);
    combine_f32<<<NTOK, blk, 0, stream>>>(y, gval, slot_of, h);
  }
  gemm_f32<true, false, false><<<dim3(OUTD / 64, NTOK / 64, 1), blk, 0, stream>>>(
      h, nullptr, dec_w, dec_b, outp, nullptr, nullptr, NTOK, HD, OUTD);
  write_loss<<<1, 1, 0, stream>>>(loss, outp + NTOK * OUTD);
}